// Round 1
// baseline (1260.797 us; speedup 1.0000x reference)
//
#include <hip/hip_runtime.h>
#include <math.h>

#define LAM 9.0f
#define EPSF 1e-8f

// ws layout (floats)
#define OFF_MMU 0
#define OFF_MLV (512*32)
#define OFF_M1  (2*512*32)
#define OFF_S   (3*512*32)          // 49152 : s[c][l] (64*32)
#define OFF_W   (OFF_S + 64*32)     // 51200 : w[b][c] (64*64)
#define OFF_TS  (OFF_W + 64*64)     // 55296 : tnode_s[c][b][l][f] (64*64*32*32)

// ---------------- kpre: M_X = W_X @ W_gc  (512x32 each, X in {mu,lv,1}) ----------------
__global__ __launch_bounds__(256) void kpre(const float* __restrict__ Wmu,
                                            const float* __restrict__ Wlv,
                                            const float* __restrict__ W1,
                                            const float* __restrict__ Wgc,
                                            float* __restrict__ ws) {
    int t = blockIdx.x * 256 + threadIdx.x;     // 3*512*32 = 49152 threads
    int m = t / (512 * 32);
    int r = t % (512 * 32);
    int h = r >> 5, f = r & 31;
    const float* W = (m == 0) ? Wmu : (m == 1) ? Wlv : W1;
    float acc = 0.f;
    for (int k = 0; k < 512; k++) acc += W[h * 512 + k] * Wgc[k * 32 + f];
    ws[m * (512 * 32) + h * 32 + f] = acc;
}

// ---------------- k1: per caption: words_sim -> adj -> s[c][l] ----------------
__global__ __launch_bounds__(256) void k1(const float* __restrict__ captions,
                                          const int* __restrict__ depends,
                                          float* __restrict__ ws) {
    int c = blockIdx.x;
    __shared__ float caps[32][65];
    __shared__ float G[32][33];
    __shared__ float adj[32][33];
    int t = threadIdx.x;
    int l2 = t & 31, l1_0 = t >> 5;
    float acc[4] = {0.f, 0.f, 0.f, 0.f};
    const float* cap = captions + (size_t)c * 32 * 1024;

    for (int kc = 0; kc < 16; kc++) {
        for (int i = t; i < 512; i += 256) {          // 32 rows x 16 float4
            int ll = i >> 4, q = i & 15;
            float4 v = *(const float4*)(cap + ll * 1024 + kc * 64 + q * 4);
            caps[ll][q * 4 + 0] = v.x; caps[ll][q * 4 + 1] = v.y;
            caps[ll][q * 4 + 2] = v.z; caps[ll][q * 4 + 3] = v.w;
        }
        __syncthreads();
        #pragma unroll 4
        for (int k = 0; k < 64; k++) {
            float cv = caps[l2][k];
            #pragma unroll
            for (int i = 0; i < 4; i++) acc[i] += caps[l1_0 + 8 * i][k] * cv;
        }
        __syncthreads();
    }
    #pragma unroll
    for (int i = 0; i < 4; i++) G[l1_0 + 8 * i][l2] = acc[i];
    // zero adj
    for (int i = t; i < 32 * 33; i += 256) ((float*)adj)[i] = 0.f;
    __syncthreads();

    // softmax rows of LAM*G  (thread per row)
    if (t < 32) {
        float mx = -1e30f;
        for (int n = 0; n < 32; n++) mx = fmaxf(mx, LAM * G[t][n]);
        float sum = 0.f;
        for (int n = 0; n < 32; n++) { float p = expf(LAM * G[t][n] - mx); G[t][n] = p; sum += p; }
        float inv = 1.f / sum;
        for (int n = 0; n < 32; n++) G[t][n] *= inv;
    }
    __syncthreads();
    if (t >= 1 && t < 30) {                 // skip dep pair 0 (mask==0)
        int d0 = depends[c * 60 + t * 2 + 0];
        int d1 = depends[c * 60 + t * 2 + 1];
        adj[d0][d1] = 1.f;
        adj[d1][d0] = 1.f;
    }
    __syncthreads();
    if (t < 32) adj[t][t] += 1.f;           // + eye (diag can be 2)
    __syncthreads();
    if (t < 32) {
        float ss = 0.f, sw = 0.f;
        for (int n = 0; n < 32; n++) { float m = adj[t][n] * G[t][n]; ss += m * m; }
        float inv = 1.f / (sqrtf(ss) + EPSF);
        for (int n = 0; n < 32; n++) sw += adj[t][n] * G[t][n] * adj[t][n];
        ws[OFF_S + c * 32 + t] = sw * inv;
    }
}

// ---------------- k2: per (c,b): attn -> leaky -> l2norm -> softmax -> wctx -> tnode_s ----------------
__global__ __launch_bounds__(256) void k2(const float* __restrict__ images,
                                          const float* __restrict__ captions,
                                          const float* __restrict__ ws_s,
                                          float* __restrict__ ts_out) {
    int c = blockIdx.x >> 6;
    int b = blockIdx.x & 63;

    __shared__ union {
        struct { float img[36][65]; float cap[32][65]; } s1;
        struct { float img2[36][33]; float cap2[32][33]; float wctx[32][33]; } s2;
    } sm;
    __shared__ float A[36][33];
    __shared__ float asmx[32][37];

    const float* img = images + (size_t)b * 36 * 1024;
    const float* cap = captions + (size_t)c * 32 * 1024;
    int t = threadIdx.x;
    int l = t & 31, r0 = t >> 5;

    // ---- stage 1: A[r][l] = sum_e img[r][e]*cap[l][e] ----
    float acc[5] = {0.f, 0.f, 0.f, 0.f, 0.f};
    for (int kc = 0; kc < 16; kc++) {
        for (int i = t; i < 576; i += 256) {          // img: 36 x 16 float4
            int rr = i >> 4, q = i & 15;
            float4 v = *(const float4*)(img + rr * 1024 + kc * 64 + q * 4);
            sm.s1.img[rr][q * 4 + 0] = v.x; sm.s1.img[rr][q * 4 + 1] = v.y;
            sm.s1.img[rr][q * 4 + 2] = v.z; sm.s1.img[rr][q * 4 + 3] = v.w;
        }
        for (int i = t; i < 512; i += 256) {          // cap: 32 x 16 float4
            int ll = i >> 4, q = i & 15;
            float4 v = *(const float4*)(cap + ll * 1024 + kc * 64 + q * 4);
            sm.s1.cap[ll][q * 4 + 0] = v.x; sm.s1.cap[ll][q * 4 + 1] = v.y;
            sm.s1.cap[ll][q * 4 + 2] = v.z; sm.s1.cap[ll][q * 4 + 3] = v.w;
        }
        __syncthreads();
        #pragma unroll 4
        for (int k = 0; k < 64; k++) {
            float cv = sm.s1.cap[l][k];
            acc[0] += sm.s1.img[r0][k] * cv;
            acc[1] += sm.s1.img[r0 + 8][k] * cv;
            acc[2] += sm.s1.img[r0 + 16][k] * cv;
            acc[3] += sm.s1.img[r0 + 24][k] * cv;
            if (r0 < 4) acc[4] += sm.s1.img[r0 + 32][k] * cv;
        }
        __syncthreads();
    }
    A[r0][l] = acc[0];
    A[r0 + 8][l] = acc[1];
    A[r0 + 16][l] = acc[2];
    A[r0 + 24][l] = acc[3];
    if (r0 < 4) A[r0 + 32][l] = acc[4];
    __syncthreads();

    // ---- leaky + l2norm over l (per region row) ----
    if (t < 36) {
        float ss = 0.f;
        for (int n = 0; n < 32; n++) {
            float v = A[t][n];
            v = (v >= 0.f) ? v : 0.1f * v;
            A[t][n] = v;
            ss += v * v;
        }
        float inv = 1.f / (sqrtf(ss) + EPSF);
        for (int n = 0; n < 32; n++) A[t][n] *= inv;
    }
    __syncthreads();
    // ---- softmax over regions (per word) -> asmx[l][r] ----
    if (t < 32) {
        float mx = -1e30f;
        for (int rr = 0; rr < 36; rr++) mx = fmaxf(mx, LAM * A[rr][t]);
        float sum = 0.f;
        for (int rr = 0; rr < 36; rr++) { float p = expf(LAM * A[rr][t] - mx); asmx[t][rr] = p; sum += p; }
        float inv = 1.f / sum;
        for (int rr = 0; rr < 36; rr++) asmx[t][rr] *= inv;
    }
    __syncthreads();

    // ---- stage 2: wctx chunks of 32 cols + blockwise cosine ----
    int e0 = t & 31;
    int lg0 = t >> 5;                 // 0..7
    int lt = t >> 3, j = t & 7;       // for tnode reduce: 8 lanes per word
    for (int f = 0; f < 32; f++) {
        for (int i = t; i < 288; i += 256) {          // img2: 36 x 8 float4
            int rr = i >> 3, q = i & 7;
            float4 v = *(const float4*)(img + rr * 1024 + f * 32 + q * 4);
            sm.s2.img2[rr][q * 4 + 0] = v.x; sm.s2.img2[rr][q * 4 + 1] = v.y;
            sm.s2.img2[rr][q * 4 + 2] = v.z; sm.s2.img2[rr][q * 4 + 3] = v.w;
        }
        if (t < 256) {                                 // cap2: 32 x 8 float4
            int ll = t >> 3, q = t & 7;
            float4 v = *(const float4*)(cap + ll * 1024 + f * 32 + q * 4);
            sm.s2.cap2[ll][q * 4 + 0] = v.x; sm.s2.cap2[ll][q * 4 + 1] = v.y;
            sm.s2.cap2[ll][q * 4 + 2] = v.z; sm.s2.cap2[ll][q * 4 + 3] = v.w;
        }
        __syncthreads();
        float wa[4] = {0.f, 0.f, 0.f, 0.f};
        #pragma unroll 4
        for (int rr = 0; rr < 36; rr++) {
            float iv = sm.s2.img2[rr][e0];
            #pragma unroll
            for (int i = 0; i < 4; i++) wa[i] += asmx[lg0 + 8 * i][rr] * iv;
        }
        #pragma unroll
        for (int i = 0; i < 4; i++) sm.s2.wctx[lg0 + 8 * i][e0] = wa[i];
        __syncthreads();
        // blockwise cosine for this 32-col block
        float num = 0.f, q2 = 0.f, w2 = 0.f;
        #pragma unroll
        for (int e = j * 4; e < j * 4 + 4; e++) {
            float qv = sm.s2.cap2[lt][e];
            float wv = sm.s2.wctx[lt][e];
            num += qv * wv; q2 += qv * qv; w2 += wv * wv;
        }
        #pragma unroll
        for (int off = 4; off >= 1; off >>= 1) {
            num += __shfl_down(num, off);
            q2  += __shfl_down(q2, off);
            w2  += __shfl_down(w2, off);
        }
        if (j == 0) {
            float den = fmaxf(sqrtf(q2) * sqrtf(w2), EPSF);
            float tn = num / den;
            ts_out[(((size_t)c * 64 + b) * 32 + lt) * 32 + f] = tn * ws_s[c * 32 + lt];
        }
        __syncthreads();
    }
}

// ---------------- k3: similarities[b][c] via folded M1 ----------------
__global__ __launch_bounds__(256) void k3(const float* __restrict__ ts_ws,
                                          const float* __restrict__ M1,
                                          const float* __restrict__ b1,
                                          const float* __restrict__ W2,
                                          const float* __restrict__ b2,
                                          float* __restrict__ out_sim) {
    int c = blockIdx.x >> 6, b = blockIdx.x & 63;
    __shared__ float ts_s[32][33];
    __shared__ float red[4];
    int t = threadIdx.x;
    const float* tsrc = ts_ws + (size_t)(c * 64 + b) * 1024;
    if (t < 256) {
        int ll = t >> 3, q = t & 7;
        float4 v = *(const float4*)(tsrc + ll * 32 + q * 4);
        ts_s[ll][q * 4 + 0] = v.x; ts_s[ll][q * 4 + 1] = v.y;
        ts_s[ll][q * 4 + 2] = v.z; ts_s[ll][q * 4 + 3] = v.w;
    }
    __syncthreads();
    float psum = 0.f;
    for (int hh = t; hh < 512; hh += 256) {
        float m1r[32];
        #pragma unroll
        for (int q = 0; q < 8; q++) {
            float4 v = *(const float4*)(M1 + hh * 32 + q * 4);
            m1r[q * 4 + 0] = v.x; m1r[q * 4 + 1] = v.y; m1r[q * 4 + 2] = v.z; m1r[q * 4 + 3] = v.w;
        }
        float bb = b1[hh], w2v = W2[hh];
        for (int ll = 0; ll < 32; ll++) {
            float d = bb;
            #pragma unroll
            for (int k = 0; k < 32; k++) d += ts_s[ll][k] * m1r[k];
            psum += tanhf(d) * w2v;
        }
    }
    #pragma unroll
    for (int off = 32; off >= 1; off >>= 1) psum += __shfl_down(psum, off);
    if ((t & 63) == 0) red[t >> 6] = psum;
    __syncthreads();
    if (t == 0) out_sim[b * 64 + c] = b2[0] + (red[0] + red[1] + red[2] + red[3]) * (1.f / 32.f);
}

// ---------------- k4: w[b][c] = softmax over c ----------------
__global__ __launch_bounds__(64) void k4(const float* __restrict__ sim, float* __restrict__ w_ws) {
    int b = blockIdx.x, t = threadIdx.x;
    float v = sim[b * 64 + t];
    float mx = v;
    #pragma unroll
    for (int off = 32; off >= 1; off >>= 1) mx = fmaxf(mx, __shfl_xor(mx, off));
    float p = expf(v - mx);
    float sum = p;
    #pragma unroll
    for (int off = 32; off >= 1; off >>= 1) sum += __shfl_xor(sum, off);
    w_ws[b * 64 + t] = p / sum;
}

// ---------------- k5: accumulate mu_word / sigma_word over captions ----------------
__global__ __launch_bounds__(512) void k5(const float* __restrict__ ts_ws,
                                          const float* __restrict__ ws,
                                          const float* __restrict__ b_mu,
                                          const float* __restrict__ b_lv,
                                          float* __restrict__ out) {
    int b = blockIdx.x >> 5, l = blockIdx.x & 31;
    int h = threadIdx.x;
    __shared__ float ts_s[64][33];
    __shared__ float w_s[64];
    const float* Mmu = ws + OFF_MMU;
    const float* Mlv = ws + OFF_MLV;
    const float* wv = ws + OFF_W;

    if (h < 64 * 8) {
        int cc = h >> 3, q = h & 7;
        float4 v = *(const float4*)(ts_ws + (((size_t)cc * 64 + b) * 32 + l) * 32 + q * 4);
        ts_s[cc][q * 4 + 0] = v.x; ts_s[cc][q * 4 + 1] = v.y;
        ts_s[cc][q * 4 + 2] = v.z; ts_s[cc][q * 4 + 3] = v.w;
    }
    if (h < 64) w_s[h] = wv[b * 64 + h];
    __syncthreads();

    float mr[32], lr[32];
    #pragma unroll
    for (int q = 0; q < 8; q++) {
        float4 v = *(const float4*)(Mmu + h * 32 + q * 4);
        mr[q * 4 + 0] = v.x; mr[q * 4 + 1] = v.y; mr[q * 4 + 2] = v.z; mr[q * 4 + 3] = v.w;
        float4 u = *(const float4*)(Mlv + h * 32 + q * 4);
        lr[q * 4 + 0] = u.x; lr[q * 4 + 1] = u.y; lr[q * 4 + 2] = u.z; lr[q * 4 + 3] = u.w;
    }
    float bm = b_mu[h], bl = b_lv[h];
    float accM = 0.f, accE = 0.f;
    for (int cc = 0; cc < 64; cc++) {
        float mu = bm, lv = bl;
        #pragma unroll
        for (int k = 0; k < 32; k++) {
            float tv = ts_s[cc][k];
            mu += tv * mr[k];
            lv += tv * lr[k];
        }
        float wc = w_s[cc];
        accM += wc * mu;
        accE += wc * (expf(lv) + mu * mu);
    }
    size_t idx = (size_t)(b * 32 + l) * 512 + h;
    out[4096 + idx] = accM;
    float var = accE - accM * accM;
    out[4096 + 64 * 32 * 512 + idx] = sqrtf(fmaxf(var, 1e-8f));
}

extern "C" void kernel_launch(void* const* d_in, const int* in_sizes, int n_in,
                              void* d_out, int out_size, void* d_ws, size_t ws_size,
                              hipStream_t stream) {
    const float* images   = (const float*)d_in[0];
    const float* captions = (const float*)d_in[1];
    const int*   depends  = (const int*)d_in[2];
    const float* Wgc = (const float*)d_in[3];
    const float* Wmu = (const float*)d_in[4];
    const float* bmu = (const float*)d_in[5];
    const float* Wlv = (const float*)d_in[6];
    const float* blv = (const float*)d_in[7];
    const float* W1  = (const float*)d_in[8];
    const float* b1  = (const float*)d_in[9];
    const float* W2  = (const float*)d_in[10];
    const float* b2  = (const float*)d_in[11];
    float* out = (float*)d_out;
    float* ws  = (float*)d_ws;

    hipLaunchKernelGGL(kpre, dim3(192), dim3(256), 0, stream, Wmu, Wlv, W1, Wgc, ws);
    hipLaunchKernelGGL(k1, dim3(64), dim3(256), 0, stream, captions, depends, ws);
    hipLaunchKernelGGL(k2, dim3(4096), dim3(256), 0, stream, images, captions, ws + OFF_S, ws + OFF_TS);
    hipLaunchKernelGGL(k3, dim3(4096), dim3(256), 0, stream, ws + OFF_TS, ws + OFF_M1, b1, W2, b2, out);
    hipLaunchKernelGGL(k4, dim3(64), dim3(64), 0, stream, out, ws + OFF_W);
    hipLaunchKernelGGL(k5, dim3(2048), dim3(512), 0, stream, ws + OFF_TS, ws, bmu, blv, out);
}

// Round 2
// 797.144 us; speedup vs baseline: 1.5816x; 1.5816x over previous
//
#include <hip/hip_runtime.h>
#include <math.h>

#define LAM 9.0f
#define EPSF 1e-8f

// ws layout (floats)
#define OFF_MMU 0
#define OFF_MLV (512*32)
#define OFF_M1  (2*512*32)
#define OFF_S   (3*512*32)              // 49152 : s[c][l] (64*32)
#define OFF_W   (OFF_S + 64*32)         // 51200 : w[b][c] (64*64)
#define OFF_TS  (OFF_W + 64*64)         // 55296 : tnode_s[c][b][l][f] (64*64*32*32)
#define OFF_ATTN (OFF_TS + 64*64*32*32) // 4249600 : attn chunk [2304][NW]

// ---------------- kpre: M_X = W_X @ W_gc (512x32 each) with LDS staging ----------------
__global__ __launch_bounds__(256) void kpre(const float* __restrict__ Wmu,
                                            const float* __restrict__ Wlv,
                                            const float* __restrict__ W1,
                                            const float* __restrict__ Wgc,
                                            float* __restrict__ ws) {
    int m = blockIdx.x >> 6;            // 0..2
    int hg = blockIdx.x & 63;           // 0..63
    int h0 = hg * 8;
    const float* W = (m == 0) ? Wmu : (m == 1) ? Wlv : W1;
    __shared__ float Gs[64][32];        // Wgc chunk [k][f]
    __shared__ float Ws[8][68];         // W rows chunk [h][k]
    int t = threadIdx.x;
    int h = t >> 5, f = t & 31;
    float acc = 0.f;
    for (int kc = 0; kc < 8; kc++) {
        for (int i = t; i < 512; i += 256) {        // Gs: 64 rows x 8 f4
            int row = i >> 3, c4 = i & 7;
            *(float4*)&Gs[row][c4 * 4] = *(const float4*)(Wgc + (kc * 64 + row) * 32 + c4 * 4);
        }
        if (t < 128) {                              // Ws: 8 rows x 16 f4
            int hh = t >> 4, c4 = t & 15;
            *(float4*)&Ws[hh][c4 * 4] = *(const float4*)(W + (size_t)(h0 + hh) * 512 + kc * 64 + c4 * 4);
        }
        __syncthreads();
        #pragma unroll 4
        for (int k = 0; k < 64; k++) acc += Ws[h][k] * Gs[k][f];
        __syncthreads();
    }
    ws[m * (512 * 32) + (h0 + h) * 32 + f] = acc;
}

// ---------------- k1: per caption: words_sim -> adj -> s[c][l] ----------------
__global__ __launch_bounds__(256) void k1(const float* __restrict__ captions,
                                          const int* __restrict__ depends,
                                          float* __restrict__ ws) {
    int c = blockIdx.x;
    __shared__ float caps[32][65];
    __shared__ float G[32][33];
    __shared__ float adj[32][33];
    int t = threadIdx.x;
    int l2 = t & 31, l1_0 = t >> 5;
    float acc[4] = {0.f, 0.f, 0.f, 0.f};
    const float* cap = captions + (size_t)c * 32 * 1024;

    for (int kc = 0; kc < 16; kc++) {
        for (int i = t; i < 512; i += 256) {
            int ll = i >> 4, q = i & 15;
            float4 v = *(const float4*)(cap + ll * 1024 + kc * 64 + q * 4);
            caps[ll][q * 4 + 0] = v.x; caps[ll][q * 4 + 1] = v.y;
            caps[ll][q * 4 + 2] = v.z; caps[ll][q * 4 + 3] = v.w;
        }
        __syncthreads();
        #pragma unroll 4
        for (int k = 0; k < 64; k++) {
            float cv = caps[l2][k];
            #pragma unroll
            for (int i = 0; i < 4; i++) acc[i] += caps[l1_0 + 8 * i][k] * cv;
        }
        __syncthreads();
    }
    #pragma unroll
    for (int i = 0; i < 4; i++) G[l1_0 + 8 * i][l2] = acc[i];
    for (int i = t; i < 32 * 33; i += 256) ((float*)adj)[i] = 0.f;
    __syncthreads();

    if (t < 32) {
        float mx = -1e30f;
        for (int n = 0; n < 32; n++) mx = fmaxf(mx, LAM * G[t][n]);
        float sum = 0.f;
        for (int n = 0; n < 32; n++) { float p = expf(LAM * G[t][n] - mx); G[t][n] = p; sum += p; }
        float inv = 1.f / sum;
        for (int n = 0; n < 32; n++) G[t][n] *= inv;
    }
    __syncthreads();
    if (t >= 1 && t < 30) {
        int d0 = depends[c * 60 + t * 2 + 0];
        int d1 = depends[c * 60 + t * 2 + 1];
        adj[d0][d1] = 1.f;
        adj[d1][d0] = 1.f;
    }
    __syncthreads();
    if (t < 32) adj[t][t] += 1.f;
    __syncthreads();
    if (t < 32) {
        float ss = 0.f, sw = 0.f;
        for (int n = 0; n < 32; n++) { float mm = adj[t][n] * G[t][n]; ss += mm * mm; }
        float inv = 1.f / (sqrtf(ss) + EPSF);
        for (int n = 0; n < 32; n++) sw += adj[t][n] * G[t][n] * adj[t][n];
        ws[OFF_S + c * 32 + t] = sw * inv;
    }
}

// ---------------- k2a: attn = IMG(2304x1024) @ CAP^T (cols n0..n0+NW) ----------------
// tile 128x64, BK=16, 256 threads, 8x4 per thread
__global__ __launch_bounds__(256) void k2a(const float* __restrict__ A,
                                           const float* __restrict__ Bm,
                                           float* __restrict__ C,
                                           int n0, int NW) {
    __shared__ float As[16][132];
    __shared__ float Bs[16][68];
    int m0 = blockIdx.x * 128;
    int nb0 = n0 + blockIdx.y * 64;
    int t = threadIdx.x;
    int tm = t >> 4, tn = t & 15;
    float acc[8][4] = {};
    for (int kc = 0; kc < 64; kc++) {
        #pragma unroll
        for (int j = 0; j < 2; j++) {
            int idx = t + j * 256;
            int row = idx >> 2, kq = idx & 3;
            float4 v = *(const float4*)(A + (size_t)(m0 + row) * 1024 + kc * 16 + kq * 4);
            As[kq * 4 + 0][row] = v.x; As[kq * 4 + 1][row] = v.y;
            As[kq * 4 + 2][row] = v.z; As[kq * 4 + 3][row] = v.w;
        }
        {
            int row = t >> 2, kq = t & 3;
            float4 v = *(const float4*)(Bm + (size_t)(nb0 + row) * 1024 + kc * 16 + kq * 4);
            Bs[kq * 4 + 0][row] = v.x; Bs[kq * 4 + 1][row] = v.y;
            Bs[kq * 4 + 2][row] = v.z; Bs[kq * 4 + 3][row] = v.w;
        }
        __syncthreads();
        #pragma unroll
        for (int kk = 0; kk < 16; kk++) {
            float a0[4], a1[4], bb[4];
            *(float4*)a0 = *(float4*)&As[kk][tm * 8];
            *(float4*)a1 = *(float4*)&As[kk][tm * 8 + 4];
            *(float4*)bb = *(float4*)&Bs[kk][tn * 4];
            #pragma unroll
            for (int i = 0; i < 4; i++)
                #pragma unroll
                for (int j2 = 0; j2 < 4; j2++) {
                    acc[i][j2]     += a0[i] * bb[j2];
                    acc[i + 4][j2] += a1[i] * bb[j2];
                }
        }
        __syncthreads();
    }
    int cw0 = nb0 - n0 + tn * 4;
    #pragma unroll
    for (int i = 0; i < 8; i++) {
        float4 v = make_float4(acc[i][0], acc[i][1], acc[i][2], acc[i][3]);
        *(float4*)(C + (size_t)(m0 + tm * 8 + i) * NW + cw0) = v;
    }
}

// ---------------- k2b: per (c,b): leaky/l2norm/softmax -> wctx -> tnode_s ----------------
__global__ __launch_bounds__(256) void k2b(const float* __restrict__ images,
                                           const float* __restrict__ captions,
                                           const float* __restrict__ attn,
                                           const float* __restrict__ s_ws,
                                           float* __restrict__ ts_out,
                                           int c0, int NW) {
    int b = blockIdx.x;
    int cw = blockIdx.y;
    int c = c0 + cw;
    __shared__ float A[36][36];         // attn tile -> asmx in [r][l] layout
    __shared__ float Ims[36][256];      // img e-chunk
    const float* img = images + (size_t)b * 36 * 1024;
    const float* cap = captions + (size_t)c * 32 * 1024;
    int t = threadIdx.x;

    for (int i = t; i < 288; i += 256) {
        int r = i >> 3, q = i & 7;
        *(float4*)&A[r][q * 4] = *(const float4*)(attn + (size_t)(b * 36 + r) * NW + cw * 32 + q * 4);
    }
    __syncthreads();
    if (t < 36) {                       // leaky + l2norm over words (per region)
        float ss = 0.f;
        #pragma unroll
        for (int l = 0; l < 32; l++) {
            float v = A[t][l];
            v = (v >= 0.f) ? v : 0.1f * v;
            A[t][l] = v; ss += v * v;
        }
        float inv = 1.f / (sqrtf(ss) + EPSF);
        #pragma unroll
        for (int l = 0; l < 32; l++) A[t][l] *= inv;
    }
    __syncthreads();
    if (t < 32) {                       // softmax over regions (per word), in place
        float mx = -1e30f;
        for (int r = 0; r < 36; r++) mx = fmaxf(mx, A[r][t]);
        mx *= LAM;
        float sum = 0.f;
        for (int r = 0; r < 36; r++) { float p = expf(LAM * A[r][t] - mx); A[r][t] = p; sum += p; }
        float inv = 1.f / sum;
        for (int r = 0; r < 36; r++) A[r][t] *= inv;
    }
    __syncthreads();

    int lg = t >> 5, fp = (t >> 3) & 3, q = t & 7;
    float sc[4];
    #pragma unroll
    for (int i = 0; i < 4; i++) sc[i] = s_ws[c * 32 + lg * 4 + i];

    for (int g = 0; g < 4; g++) {
        for (int i = t; i < 2304; i += 256) {
            int r = i >> 6, c4 = i & 63;
            *(float4*)&Ims[r][c4 * 4] = *(const float4*)(img + (size_t)r * 1024 + g * 256 + c4 * 4);
        }
        __syncthreads();
        float acc[4][2][4] = {};
        for (int r = 0; r < 36; r++) {
            float4 a  = *(float4*)&A[r][lg * 4];
            float4 i0 = *(float4*)&Ims[r][(fp * 2 + 0) * 32 + q * 4];
            float4 i1 = *(float4*)&Ims[r][(fp * 2 + 1) * 32 + q * 4];
            float av[4]  = {a.x, a.y, a.z, a.w};
            float iv0[4] = {i0.x, i0.y, i0.z, i0.w};
            float iv1[4] = {i1.x, i1.y, i1.z, i1.w};
            #pragma unroll
            for (int i = 0; i < 4; i++)
                #pragma unroll
                for (int e = 0; e < 4; e++) {
                    acc[i][0][e] += av[i] * iv0[e];
                    acc[i][1][e] += av[i] * iv1[e];
                }
        }
        #pragma unroll
        for (int f2 = 0; f2 < 2; f2++) {
            int fglob = g * 8 + fp * 2 + f2;
            #pragma unroll
            for (int i = 0; i < 4; i++) {
                int l = lg * 4 + i;
                float4 cv = *(const float4*)(cap + (size_t)l * 1024 + fglob * 32 + q * 4);
                float cvv[4] = {cv.x, cv.y, cv.z, cv.w};
                float num = 0.f, w2 = 0.f, q2 = 0.f;
                #pragma unroll
                for (int e = 0; e < 4; e++) {
                    float wv = acc[i][f2][e];
                    num += cvv[e] * wv; w2 += wv * wv; q2 += cvv[e] * cvv[e];
                }
                #pragma unroll
                for (int off = 4; off >= 1; off >>= 1) {
                    num += __shfl_down(num, off);
                    w2  += __shfl_down(w2, off);
                    q2  += __shfl_down(q2, off);
                }
                if (q == 0) {
                    float den = fmaxf(sqrtf(q2) * sqrtf(w2), EPSF);
                    ts_out[(((size_t)c * 64 + b) * 32 + l) * 32 + fglob] = (num / den) * sc[i];
                }
            }
        }
        __syncthreads();
    }
}

// ---------------- k3: similarities[b][c] via folded M1 ----------------
__global__ __launch_bounds__(256) void k3(const float* __restrict__ ts_ws,
                                          const float* __restrict__ M1,
                                          const float* __restrict__ b1,
                                          const float* __restrict__ W2,
                                          const float* __restrict__ b2,
                                          float* __restrict__ out_sim) {
    int c = blockIdx.x >> 6, b = blockIdx.x & 63;
    __shared__ float ts_s[32][33];
    __shared__ float red[4];
    int t = threadIdx.x;
    const float* tsrc = ts_ws + (size_t)(c * 64 + b) * 1024;
    if (t < 256) {
        int ll = t >> 3, q = t & 7;
        float4 v = *(const float4*)(tsrc + ll * 32 + q * 4);
        ts_s[ll][q * 4 + 0] = v.x; ts_s[ll][q * 4 + 1] = v.y;
        ts_s[ll][q * 4 + 2] = v.z; ts_s[ll][q * 4 + 3] = v.w;
    }
    __syncthreads();
    float psum = 0.f;
    for (int hh = t; hh < 512; hh += 256) {
        float m1r[32];
        #pragma unroll
        for (int q = 0; q < 8; q++) {
            float4 v = *(const float4*)(M1 + hh * 32 + q * 4);
            m1r[q * 4 + 0] = v.x; m1r[q * 4 + 1] = v.y; m1r[q * 4 + 2] = v.z; m1r[q * 4 + 3] = v.w;
        }
        float bb = b1[hh], w2v = W2[hh];
        for (int ll = 0; ll < 32; ll++) {
            float d = bb;
            #pragma unroll
            for (int k = 0; k < 32; k++) d += ts_s[ll][k] * m1r[k];
            psum += tanhf(d) * w2v;
        }
    }
    #pragma unroll
    for (int off = 32; off >= 1; off >>= 1) psum += __shfl_down(psum, off);
    if ((t & 63) == 0) red[t >> 6] = psum;
    __syncthreads();
    if (t == 0) out_sim[b * 64 + c] = b2[0] + (red[0] + red[1] + red[2] + red[3]) * (1.f / 32.f);
}

// ---------------- k4: w[b][c] = softmax over c ----------------
__global__ __launch_bounds__(64) void k4(const float* __restrict__ sim, float* __restrict__ w_ws) {
    int b = blockIdx.x, t = threadIdx.x;
    float v = sim[b * 64 + t];
    float mx = v;
    #pragma unroll
    for (int off = 32; off >= 1; off >>= 1) mx = fmaxf(mx, __shfl_xor(mx, off));
    float p = expf(v - mx);
    float sum = p;
    #pragma unroll
    for (int off = 32; off >= 1; off >>= 1) sum += __shfl_xor(sum, off);
    w_ws[b * 64 + t] = p / sum;
}

// ---------------- k5: accumulate mu_word / sigma_word over captions ----------------
__global__ __launch_bounds__(512) void k5(const float* __restrict__ ts_ws,
                                          const float* __restrict__ ws,
                                          const float* __restrict__ b_mu,
                                          const float* __restrict__ b_lv,
                                          float* __restrict__ out) {
    int b = blockIdx.x >> 5, l = blockIdx.x & 31;
    int h = threadIdx.x;
    __shared__ float ts_s[64][33];
    __shared__ float w_s[64];
    const float* Mmu = ws + OFF_MMU;
    const float* Mlv = ws + OFF_MLV;
    const float* wv = ws + OFF_W;

    if (h < 64 * 8) {
        int cc = h >> 3, q = h & 7;
        float4 v = *(const float4*)(ts_ws + (((size_t)cc * 64 + b) * 32 + l) * 32 + q * 4);
        ts_s[cc][q * 4 + 0] = v.x; ts_s[cc][q * 4 + 1] = v.y;
        ts_s[cc][q * 4 + 2] = v.z; ts_s[cc][q * 4 + 3] = v.w;
    }
    if (h < 64) w_s[h] = wv[b * 64 + h];
    __syncthreads();

    float mr[32], lr[32];
    #pragma unroll
    for (int q = 0; q < 8; q++) {
        float4 v = *(const float4*)(Mmu + h * 32 + q * 4);
        mr[q * 4 + 0] = v.x; mr[q * 4 + 1] = v.y; mr[q * 4 + 2] = v.z; mr[q * 4 + 3] = v.w;
        float4 u = *(const float4*)(Mlv + h * 32 + q * 4);
        lr[q * 4 + 0] = u.x; lr[q * 4 + 1] = u.y; lr[q * 4 + 2] = u.z; lr[q * 4 + 3] = u.w;
    }
    float bm = b_mu[h], bl = b_lv[h];
    float accM = 0.f, accE = 0.f;
    for (int cc = 0; cc < 64; cc++) {
        float mu = bm, lv = bl;
        #pragma unroll
        for (int k = 0; k < 32; k++) {
            float tv = ts_s[cc][k];
            mu += tv * mr[k];
            lv += tv * lr[k];
        }
        float wc = w_s[cc];
        accM += wc * mu;
        accE += wc * (expf(lv) + mu * mu);
    }
    size_t idx = (size_t)(b * 32 + l) * 512 + h;
    out[4096 + idx] = accM;
    float var = accE - accM * accM;
    out[4096 + 64 * 32 * 512 + idx] = sqrtf(fmaxf(var, 1e-8f));
}

extern "C" void kernel_launch(void* const* d_in, const int* in_sizes, int n_in,
                              void* d_out, int out_size, void* d_ws, size_t ws_size,
                              hipStream_t stream) {
    const float* images   = (const float*)d_in[0];
    const float* captions = (const float*)d_in[1];
    const int*   depends  = (const int*)d_in[2];
    const float* Wgc = (const float*)d_in[3];
    const float* Wmu = (const float*)d_in[4];
    const float* bmu = (const float*)d_in[5];
    const float* Wlv = (const float*)d_in[6];
    const float* blv = (const float*)d_in[7];
    const float* W1  = (const float*)d_in[8];
    const float* b1  = (const float*)d_in[9];
    const float* W2  = (const float*)d_in[10];
    const float* b2  = (const float*)d_in[11];
    float* out = (float*)d_out;
    float* ws  = (float*)d_ws;

    hipLaunchKernelGGL(kpre, dim3(192), dim3(256), 0, stream, Wmu, Wlv, W1, Wgc, ws);
    hipLaunchKernelGGL(k1, dim3(64), dim3(256), 0, stream, captions, depends, ws);

    // adaptive attn-chunk width (captions-dim columns), prefer full 2048
    int NW = 2048;
    while (NW > 32 && ((size_t)OFF_ATTN + (size_t)2304 * NW) * 4 > ws_size) NW >>= 1;
    for (int n0 = 0; n0 < 2048; n0 += NW) {
        hipLaunchKernelGGL(k2a, dim3(18, NW / 64), dim3(256), 0, stream,
                           images, captions, ws + OFF_ATTN, n0, NW);
        hipLaunchKernelGGL(k2b, dim3(64, NW / 32), dim3(256), 0, stream,
                           images, captions, ws + OFF_ATTN, ws + OFF_S, ws + OFF_TS, n0 / 32, NW);
    }

    hipLaunchKernelGGL(k3, dim3(4096), dim3(256), 0, stream, ws + OFF_TS, ws + OFF_M1, b1, W2, b2, out);
    hipLaunchKernelGGL(k4, dim3(64), dim3(64), 0, stream, out, ws + OFF_W);
    hipLaunchKernelGGL(k5, dim3(2048), dim3(512), 0, stream, ws + OFF_TS, ws, bmu, blv, out);
}